// Round 7
// baseline (283.765 us; speedup 1.0000x reference)
//
#include <hip/hip_runtime.h>

#define NN 200000      // nodes; D=128 features, 40 classes (padded to 48 in wt)
#define NW 13          // waves per block: 3328 waves -> 12500/3328 = 3.76 -> 4 rounds (was 5)
#define NBLK 256       // persistent blocks (1 per CU; LDS pins 1 block/CU)
#define NT 12500       // tiles of 16 rows: 12500*16 = NN exactly
#define WSTRIDE (NBLK * NW)   // 3328 global waves

typedef __attribute__((ext_vector_type(8))) short bf16x8;
typedef __attribute__((ext_vector_type(4))) float f32x4;
typedef __attribute__((ext_vector_type(4))) unsigned int u32x4;

// round-to-nearest-even fp32 -> bf16 bits (prep kernel only)
static __device__ __forceinline__ short f2bf(float f) {
    unsigned u = __builtin_bit_cast(unsigned, f);
    u += 0x7fffu + ((u >> 16) & 1u);
    return (short)(u >> 16);
}

// pack 2 floats -> 2 bf16 in one u32 (round-half-up)
static __device__ __forceinline__ unsigned pk2(float a, float b) {
    unsigned ua = __builtin_bit_cast(unsigned, a) + 0x8000u;
    unsigned ub = __builtin_bit_cast(unsigned, b) + 0x8000u;
    return __builtin_amdgcn_perm(ub, ua, 0x07060302u);
}

// XOR-swizzled LDS offset for element (r, k) of a [*,128] bf16 table.
// 16B chunks xored with (r&15) -> conflict-free ds_read_b128 fragments.
static __device__ __forceinline__ int swz(int r, int k) {
    return (r << 7) + (((k >> 3) ^ (r & 15)) << 3) + (k & 7);
}

// Pre-transpose + bf16-convert weights into workspace (elements):
// [0) Wt0[n][k]=W0[k][n] 128x128 | [16384) Wt1 | [32768) Wt2 | [49152) Wt3 48x128.
// W3 pad rows 40-45 (cols .. ) hide the f32 biases b0|b1|b2 (768 shorts at
// element 54272): those B-rows only feed output cols 40-47, which are
// val2-masked in every consumer -> arbitrary bits are safe there.
__global__ void prep_weights_k(const float* __restrict__ W0, const float* __restrict__ W1,
                               const float* __restrict__ W2, const float* __restrict__ W3,
                               const float* __restrict__ b0, const float* __restrict__ b1,
                               const float* __restrict__ b2, short* __restrict__ wt) {
    int e = blockIdx.x * 256 + threadIdx.x;   // 216 blocks * 256 = 55296
    if (e < 49152) {
        int l = e >> 14;
        int i = e & 16383;
        int n = i >> 7, k = i & 127;
        const float* W = (l == 0) ? W0 : ((l == 1) ? W1 : W2);
        wt[e] = f2bf(W[(k << 7) + n]);
    } else if (e < 55296) {
        int i = e - 49152;
        int n = i >> 7, k = i & 127;
        short v = 0;
        if (n < 40) {
            v = f2bf(W3[k * 40 + n]);
        } else {
            int j2 = e - 54272;              // n>=40 => e>=54272
            if (j2 < 768) {                  // bias stash: float j2>>1, half j2&1
                int f = j2 >> 1, lyr = f >> 7, c = f & 127;
                const float* B = (lyr == 0) ? b0 : ((lyr == 1) ? b1 : b2);
                unsigned u = __builtin_bit_cast(unsigned, B[c]);
                v = (short)((j2 & 1) ? (u >> 16) : (u & 0xffffu));
            }
        }
        wt[e] = v;
    }
}

// Persistent fused 4-layer MLP + log_softmax. 13 waves/block:
//  - 3328 waves, 12500 tiles -> 3.76 tiles/wave -> 4-round makespan
//    (12 waves gave 4.07 -> 5 rounds: blocks 0-17 ran a 5th round while
//    238 CUs idled ~20% of wall time; occupancy counter showed the tail).
//  - LDS = 110592 (sW, all 4 layers swizzled) + 13*4096 (sA) = 163840 exact.
//  - biases live in W3's pad rows inside sW (stashed by prep); folded into
//    the ACC INIT of each layer (acc = bias, not zero) -> -96 VALU adds/tile.
//  - x prefetch: loads issued after epilogue(2); packed INCREMENTALLY inside
//    the layer-3 MFMA loop so raw[8] (32 regs) dies progressively -> peak
//    demand ~73 regs, fits the expected ~72-84 grant without spill.
__global__ __launch_bounds__(832) __attribute__((amdgpu_waves_per_eu(4, 4)))
void mlp_fused_k(const float* __restrict__ x, const short* __restrict__ wt,
                 const float* __restrict__ b3, float* __restrict__ out) {
    __shared__ __align__(16) short sW[55296];       // all 4 layers + bias stash
    __shared__ __align__(16) short sA[NW][2048];    // per-wave activation slices

    const int tid  = (int)threadIdx.x;
    const int lane = tid & 63;
    const int wv   = tid >> 6;       // wave 0..12
    const int m    = lane & 15;      // row (A) / col (B,C) within 16-tile
    const int quad = lane >> 4;      // 0..3
    short* sAw = &sA[wv][0];

    // ---- stage ALL weights global->LDS (swizzled): 6912 chunks = 8*832 + 256 ----
    {
        const u32x4* src = (const u32x4*)wt;
        #pragma unroll
        for (int i = 0; i < 8; ++i) {
            int q = tid + i * 832;
            int R = q >> 4, c = q & 15;
            *(u32x4*)&sW[(R << 7) + ((c ^ (R & 15)) << 3)] = src[q];
        }
        if (tid < 256) {
            int q = 6656 + tid;
            int R = q >> 4, c = q & 15;
            *(u32x4*)&sW[(R << 7) + ((c ^ (R & 15)) << 3)] = src[q];
        }
    }
    __syncthreads();   // the ONLY barrier

    // layer-3 bias: only 3 regs, fine to hoist
    const bool val2 = (m < 8);
    const float b3v0 = b3[m], b3v1 = b3[16 + m], b3v2 = val2 ? b3[32 + m] : 0.f;

    // bias_L[col], col=(ct<<4)+m, read from the stash in sW (swz-mapped f32)
    auto biasld = [&](int lyr, int ct) -> float {
        int f = (lyr << 7) + (ct << 4) + m;     // float index in stash
        int r = 424 + (f >> 6);                 // element 54272 = row 424
        int k = (f & 63) << 1;
        return *(const float*)&sW[swz(r, k)];
    };

    f32x4 acc[8];

    // SiLU + bf16 -> sAw (bias already folded into acc init)
    auto epilogue = [&]() {
        #pragma unroll
        for (int ct = 0; ct < 8; ++ct)
            #pragma unroll
            for (int r = 0; r < 4; ++r) {
                float v = acc[ct][r];
                float h = v * __builtin_amdgcn_rcpf(1.f + __expf(-v));
                int rl = (quad << 2) + r;                // C/D: row = quad*4+reg
                unsigned u = __builtin_bit_cast(unsigned, h) + 0x8000u;
                sAw[swz(rl, (ct << 4) + m)] = (short)(u >> 16);
            }
    };

    // dense layer: acc init = bias(lyr); A from wave-private slice, B from sW
    auto dense = [&](int lbase, int lyr) {
        #pragma unroll
        for (int ct = 0; ct < 8; ++ct) {
            float bb = biasld(lyr, ct);
            #pragma unroll
            for (int r = 0; r < 4; ++r) acc[ct][r] = bb;
        }
        __builtin_amdgcn_s_setprio(1);
        #pragma unroll
        for (int ks = 0; ks < 4; ++ks) {
            int kk = (ks << 5) + (quad << 3);
            bf16x8 a0 = *(const bf16x8*)&sAw[swz(m, kk)];
            #pragma unroll
            for (int ct = 0; ct < 8; ++ct) {
                bf16x8 b = *(const bf16x8*)&sW[lbase + swz((ct << 4) + m, kk)];
                acc[ct] = __builtin_amdgcn_mfma_f32_16x16x32_bf16(a0, b, acc[ct], 0, 0, 0);
            }
        }
        __builtin_amdgcn_s_setprio(0);
    };

    // ---- persistent tile loop; xp loop-carried, packed during layer 3 ----
    int t = (int)blockIdx.x * NW + wv;       // first tile for this wave (< WSTRIDE)
    u32x4 xp[4];
    {
        f32x4 raw[8];
        const f32x4* p = (const f32x4*)(x + ((long)(t * 16 + m) << 7)) + quad * 2;
        #pragma unroll
        for (int ks = 0; ks < 4; ++ks) { raw[ks * 2] = p[ks * 8]; raw[ks * 2 + 1] = p[ks * 8 + 1]; }
        #pragma unroll
        for (int ks = 0; ks < 4; ++ks) {
            f32x4 va = raw[ks * 2], vb = raw[ks * 2 + 1];
            u32x4 ua;
            ua[0] = pk2(va[0], va[1]); ua[1] = pk2(va[2], va[3]);
            ua[2] = pk2(vb[0], vb[1]); ua[3] = pk2(vb[2], vb[3]);
            xp[ks] = ua;
        }
    }

    while (true) {
        // layer 0: acc init = bias0; A from packed regs
        #pragma unroll
        for (int ct = 0; ct < 8; ++ct) {
            float bb = biasld(0, ct);
            #pragma unroll
            for (int r = 0; r < 4; ++r) acc[ct][r] = bb;
        }
        __builtin_amdgcn_s_setprio(1);
        #pragma unroll
        for (int ks = 0; ks < 4; ++ks) {
            bf16x8 a0 = __builtin_bit_cast(bf16x8, xp[ks]);
            int kk = (ks << 5) + (quad << 3);
            #pragma unroll
            for (int ct = 0; ct < 8; ++ct) {
                bf16x8 b = *(const bf16x8*)&sW[swz((ct << 4) + m, kk)];
                acc[ct] = __builtin_amdgcn_mfma_f32_16x16x32_bf16(a0, b, acc[ct], 0, 0, 0);
            }
        }
        __builtin_amdgcn_s_setprio(0);
        epilogue();
        dense(16384, 1);
        epilogue();
        dense(32768, 2);
        epilogue();

        int tn = t + WSTRIDE;
        bool has = tn < NT;                   // wave-uniform
        f32x4 raw[8];
        if (has) {
            const f32x4* p = (const f32x4*)(x + ((long)(tn * 16 + m) << 7)) + quad * 2;
            #pragma unroll
            for (int ks = 0; ks < 4; ++ks) { raw[ks * 2] = p[ks * 8]; raw[ks * 2 + 1] = p[ks * 8 + 1]; }
        }

        // layer 3 (48 padded cols; pad rows are bias bits -> cols 40-47 masked)
        // + incremental pack of next tile's x (raw dies pair-by-pair)
        f32x4 c3[3];
        #pragma unroll
        for (int r = 0; r < 4; ++r) { c3[0][r] = b3v0; c3[1][r] = b3v1; c3[2][r] = b3v2; }
        __builtin_amdgcn_s_setprio(1);
        #pragma unroll
        for (int ks = 0; ks < 4; ++ks) {
            int kk = (ks << 5) + (quad << 3);
            bf16x8 a0 = *(const bf16x8*)&sAw[swz(m, kk)];
            #pragma unroll
            for (int ct = 0; ct < 3; ++ct) {
                bf16x8 b = *(const bf16x8*)&sW[49152 + swz((ct << 4) + m, kk)];
                c3[ct] = __builtin_amdgcn_mfma_f32_16x16x32_bf16(a0, b, c3[ct], 0, 0, 0);
            }
            if (has) {
                f32x4 va = raw[ks * 2], vb = raw[ks * 2 + 1];
                u32x4 ua;
                ua[0] = pk2(va[0], va[1]); ua[1] = pk2(va[2], va[3]);
                ua[2] = pk2(vb[0], vb[1]); ua[3] = pk2(vb[2], vb[3]);
                xp[ks] = ua;
            }
        }
        __builtin_amdgcn_s_setprio(0);

        #pragma unroll
        for (int r = 0; r < 4; ++r) {
            float v0 = c3[0][r];
            float v1 = c3[1][r];
            float v2 = c3[2][r];
            float mx = fmaxf(v0, v1);
            mx = val2 ? fmaxf(mx, v2) : mx;
            #pragma unroll
            for (int s = 1; s < 16; s <<= 1)
                mx = fmaxf(mx, __shfl_xor(mx, s, 64));
            float sm = __expf(v0 - mx) + __expf(v1 - mx) + (val2 ? __expf(v2 - mx) : 0.f);
            #pragma unroll
            for (int s = 1; s < 16; s <<= 1)
                sm += __shfl_xor(sm, s, 64);
            float L = mx + __logf(sm);
            int grow = t * 16 + (quad << 2) + r;   // C/D: row = quad*4+reg
            float* orow = out + (long)grow * 40;
            orow[m]      = v0 - L;
            orow[16 + m] = v1 - L;
            if (val2) orow[32 + m] = v2 - L;
        }

        if (!has) break;
        t = tn;
    }
}

extern "C" void kernel_launch(void* const* d_in, const int* in_sizes, int n_in,
                              void* d_out, int out_size, void* d_ws, size_t ws_size,
                              hipStream_t stream) {
    const float* x   = (const float*)d_in[0];
    // d_in[1] = edge_index (unused: ChebConv K=1 ignores the Laplacian)
    const float* W0  = (const float*)d_in[2];
    const float* bb0 = (const float*)d_in[3];
    const float* W1  = (const float*)d_in[4];
    const float* bb1 = (const float*)d_in[5];
    const float* W2  = (const float*)d_in[6];
    const float* bb2 = (const float*)d_in[7];
    const float* W3  = (const float*)d_in[8];
    const float* bb3 = (const float*)d_in[9];
    short* wt  = (short*)d_ws;         // 110592 B of bf16 transposed weights + bias stash
    float* out = (float*)d_out;

    hipLaunchKernelGGL(prep_weights_k, dim3(216), dim3(256), 0, stream,
                       W0, W1, W2, W3, bb0, bb1, bb2, wt);
    hipLaunchKernelGGL(mlp_fused_k, dim3(NBLK), dim3(832), 0, stream,
                       x, wt, bb3, out);
}

// Round 8
// 242.104 us; speedup vs baseline: 1.1721x; 1.1721x over previous
//
#include <hip/hip_runtime.h>

#define NN 200000      // nodes; D=128 features, 40 classes (padded to 48 in wt)
#define NW 13          // waves per block: 3328 waves -> ceil(12500/3328) = 4 rounds (12 waves -> 5)
#define NBLK 256       // persistent blocks (1 per CU; LDS pins 1 block/CU)
#define NT 12500       // tiles of 16 rows: 12500*16 = NN exactly
#define WSTRIDE (NBLK * NW)   // 3328 global waves

typedef __attribute__((ext_vector_type(8))) short bf16x8;
typedef __attribute__((ext_vector_type(4))) float f32x4;
typedef __attribute__((ext_vector_type(4))) unsigned int u32x4;

// round-to-nearest-even fp32 -> bf16 bits (prep kernel only)
static __device__ __forceinline__ short f2bf(float f) {
    unsigned u = __builtin_bit_cast(unsigned, f);
    u += 0x7fffu + ((u >> 16) & 1u);
    return (short)(u >> 16);
}

// pack 2 floats -> 2 bf16 in one u32 (round-half-up)
static __device__ __forceinline__ unsigned pk2(float a, float b) {
    unsigned ua = __builtin_bit_cast(unsigned, a) + 0x8000u;
    unsigned ub = __builtin_bit_cast(unsigned, b) + 0x8000u;
    return __builtin_amdgcn_perm(ub, ua, 0x07060302u);
}

// XOR-swizzled LDS offset for element (r, k) of a [*,128] bf16 table.
// 16B chunks xored with (r&15) -> conflict-free ds_read_b128 fragments.
static __device__ __forceinline__ int swz(int r, int k) {
    return (r << 7) + (((k >> 3) ^ (r & 15)) << 3) + (k & 7);
}

// Pre-transpose + bf16-convert weights into workspace (elements):
// [0) Wt0[n][k]=W0[k][n] 128x128 | [16384) Wt1 | [32768) Wt2 | [49152) Wt3 48x128.
// W3 pad rows 40-47 hide the f32 biases b0|b1|b2 (768 shorts at element
// 54272): those B-rows only feed output cols 40-47, which are val2-masked
// in every consumer -> arbitrary bits are safe there. (Harness-verified R7.)
__global__ void prep_weights_k(const float* __restrict__ W0, const float* __restrict__ W1,
                               const float* __restrict__ W2, const float* __restrict__ W3,
                               const float* __restrict__ b0, const float* __restrict__ b1,
                               const float* __restrict__ b2, short* __restrict__ wt) {
    int e = blockIdx.x * 256 + threadIdx.x;   // 216 blocks * 256 = 55296
    if (e < 49152) {
        int l = e >> 14;
        int i = e & 16383;
        int n = i >> 7, k = i & 127;
        const float* W = (l == 0) ? W0 : ((l == 1) ? W1 : W2);
        wt[e] = f2bf(W[(k << 7) + n]);
    } else if (e < 55296) {
        int i = e - 49152;
        int n = i >> 7, k = i & 127;
        short v = 0;
        if (n < 40) {
            v = f2bf(W3[k * 40 + n]);
        } else {
            int j2 = e - 54272;              // n>=40 => e>=54272
            if (j2 < 768) {                  // bias stash: float j2>>1, half j2&1
                int f = j2 >> 1, lyr = f >> 7, c = f & 127;
                const float* B = (lyr == 0) ? b0 : ((lyr == 1) ? b1 : b2);
                unsigned u = __builtin_bit_cast(unsigned, B[c]);
                v = (short)((j2 & 1) ? (u >> 16) : (u & 0xffffu));
            }
        }
        wt[e] = v;
    }
}

// Persistent fused 4-layer MLP + log_softmax. 13 waves/block, 64-VGPR-CLEAN:
//  - blocks >768 threads always get a 64-reg grant (R1/R3/R4/R7: every
//    waves-per-eu spelling ignored). R7's loop-carried prefetch spilled
//    ~108MB/side; R5 PROVED the cold-load-at-top structure fits 64 clean.
//  - this kernel = R5's register-clean loop + all 4 layers AND biases
//    resident in sW (no volatile L2 reads - R5's actual slowdown) + setprio.
//  - 3328 waves -> 4-round makespan (12-wave R6 had a 5th round with 7% of
//    waves active ~20% of wall time); cold-load latency is covered by
//    3.25 waves/SIMD of TLP.
//  - biases folded into the ACC INIT of each layer (acc = bias, not zero).
// LDS = 110592 (sW) + 13*4096 (sA) = 163840 B exact -> 1 block/CU.
__global__ __launch_bounds__(832)
void mlp_fused_k(const float* __restrict__ x, const short* __restrict__ wt,
                 const float* __restrict__ b3, float* __restrict__ out) {
    __shared__ __align__(16) short sW[55296];       // all 4 layers + bias stash
    __shared__ __align__(16) short sA[NW][2048];    // per-wave activation slices

    const int tid  = (int)threadIdx.x;
    const int lane = tid & 63;
    const int wv   = tid >> 6;       // wave 0..12
    const int m    = lane & 15;      // row (A) / col (B,C) within 16-tile
    const int quad = lane >> 4;      // 0..3
    short* sAw = &sA[wv][0];

    // ---- stage ALL weights global->LDS (swizzled): 6912 chunks = 8*832 + 256 ----
    {
        const u32x4* src = (const u32x4*)wt;
        #pragma unroll
        for (int i = 0; i < 8; ++i) {
            int q = tid + i * 832;
            int R = q >> 4, c = q & 15;
            *(u32x4*)&sW[(R << 7) + ((c ^ (R & 15)) << 3)] = src[q];
        }
        if (tid < 256) {
            int q = 6656 + tid;
            int R = q >> 4, c = q & 15;
            *(u32x4*)&sW[(R << 7) + ((c ^ (R & 15)) << 3)] = src[q];
        }
    }
    __syncthreads();   // the ONLY barrier

    // layer-3 bias: only 3 regs, fine to hoist
    const bool val2 = (m < 8);
    const float b3v0 = b3[m], b3v1 = b3[16 + m], b3v2 = val2 ? b3[32 + m] : 0.f;

    // bias_L[col], col=(ct<<4)+m, read from the stash in sW (swz-mapped f32)
    auto biasld = [&](int lyr, int ct) -> float {
        int f = (lyr << 7) + (ct << 4) + m;     // float index in stash
        int r = 424 + (f >> 6);                 // element 54272 = row 424
        int k = (f & 63) << 1;
        return *(const float*)&sW[swz(r, k)];
    };

    f32x4 acc[8];

    // SiLU + bf16 -> sAw (bias already folded into acc init)
    auto epilogue = [&]() {
        #pragma unroll
        for (int ct = 0; ct < 8; ++ct)
            #pragma unroll
            for (int r = 0; r < 4; ++r) {
                float v = acc[ct][r];
                float h = v * __builtin_amdgcn_rcpf(1.f + __expf(-v));
                int rl = (quad << 2) + r;                // C/D: row = quad*4+reg
                unsigned u = __builtin_bit_cast(unsigned, h) + 0x8000u;
                sAw[swz(rl, (ct << 4) + m)] = (short)(u >> 16);
            }
    };

    // dense layer: acc init = bias(lyr); A from wave-private slice, B from sW
    auto dense = [&](int lbase, int lyr) {
        #pragma unroll
        for (int ct = 0; ct < 8; ++ct) {
            float bb = biasld(lyr, ct);
            #pragma unroll
            for (int r = 0; r < 4; ++r) acc[ct][r] = bb;
        }
        __builtin_amdgcn_s_setprio(1);
        #pragma unroll
        for (int ks = 0; ks < 4; ++ks) {
            int kk = (ks << 5) + (quad << 3);
            bf16x8 a0 = *(const bf16x8*)&sAw[swz(m, kk)];
            #pragma unroll
            for (int ct = 0; ct < 8; ++ct) {
                bf16x8 b = *(const bf16x8*)&sW[lbase + swz((ct << 4) + m, kk)];
                acc[ct] = __builtin_amdgcn_mfma_f32_16x16x32_bf16(a0, b, acc[ct], 0, 0, 0);
            }
        }
        __builtin_amdgcn_s_setprio(0);
    };

    // ---- persistent tile loop; x loaded + packed at tile top (R5-proven
    //      register-clean: raw[8] dies before the first MFMA; nothing big
    //      is loop-carried -> fits the 64-reg grant without spill) ----
    for (int t = (int)blockIdx.x * NW + wv; t < NT; t += WSTRIDE) {
        u32x4 xp[4];
        {
            f32x4 raw[8];
            const f32x4* p = (const f32x4*)(x + ((long)(t * 16 + m) << 7)) + quad * 2;
            #pragma unroll
            for (int ks = 0; ks < 4; ++ks) {
                raw[ks * 2]     = p[ks * 8];
                raw[ks * 2 + 1] = p[ks * 8 + 1];
            }
            #pragma unroll
            for (int ks = 0; ks < 4; ++ks) {
                f32x4 va = raw[ks * 2], vb = raw[ks * 2 + 1];
                u32x4 ua;
                ua[0] = pk2(va[0], va[1]); ua[1] = pk2(va[2], va[3]);
                ua[2] = pk2(vb[0], vb[1]); ua[3] = pk2(vb[2], vb[3]);
                xp[ks] = ua;
            }
        }

        // layer 0: acc init = bias0; A from packed regs
        #pragma unroll
        for (int ct = 0; ct < 8; ++ct) {
            float bb = biasld(0, ct);
            #pragma unroll
            for (int r = 0; r < 4; ++r) acc[ct][r] = bb;
        }
        __builtin_amdgcn_s_setprio(1);
        #pragma unroll
        for (int ks = 0; ks < 4; ++ks) {
            bf16x8 a0 = __builtin_bit_cast(bf16x8, xp[ks]);
            int kk = (ks << 5) + (quad << 3);
            #pragma unroll
            for (int ct = 0; ct < 8; ++ct) {
                bf16x8 b = *(const bf16x8*)&sW[swz((ct << 4) + m, kk)];
                acc[ct] = __builtin_amdgcn_mfma_f32_16x16x32_bf16(a0, b, acc[ct], 0, 0, 0);
            }
        }
        __builtin_amdgcn_s_setprio(0);
        epilogue();
        dense(16384, 1);
        epilogue();
        dense(32768, 2);
        epilogue();

        // layer 3 (48 padded cols; pad rows are bias bits -> cols 40-47 masked)
        f32x4 c3[3];
        #pragma unroll
        for (int r = 0; r < 4; ++r) { c3[0][r] = b3v0; c3[1][r] = b3v1; c3[2][r] = b3v2; }
        __builtin_amdgcn_s_setprio(1);
        #pragma unroll
        for (int ks = 0; ks < 4; ++ks) {
            int kk = (ks << 5) + (quad << 3);
            bf16x8 a0 = *(const bf16x8*)&sAw[swz(m, kk)];
            #pragma unroll
            for (int ct = 0; ct < 3; ++ct) {
                bf16x8 b = *(const bf16x8*)&sW[49152 + swz((ct << 4) + m, kk)];
                c3[ct] = __builtin_amdgcn_mfma_f32_16x16x32_bf16(a0, b, c3[ct], 0, 0, 0);
            }
        }
        __builtin_amdgcn_s_setprio(0);

        #pragma unroll
        for (int r = 0; r < 4; ++r) {
            float v0 = c3[0][r];
            float v1 = c3[1][r];
            float v2 = c3[2][r];
            float mx = fmaxf(v0, v1);
            mx = val2 ? fmaxf(mx, v2) : mx;
            #pragma unroll
            for (int s = 1; s < 16; s <<= 1)
                mx = fmaxf(mx, __shfl_xor(mx, s, 64));
            float sm = __expf(v0 - mx) + __expf(v1 - mx) + (val2 ? __expf(v2 - mx) : 0.f);
            #pragma unroll
            for (int s = 1; s < 16; s <<= 1)
                sm += __shfl_xor(sm, s, 64);
            float L = mx + __logf(sm);
            int grow = t * 16 + (quad << 2) + r;   // C/D: row = quad*4+reg
            float* orow = out + (long)grow * 40;
            orow[m]      = v0 - L;
            orow[16 + m] = v1 - L;
            if (val2) orow[32 + m] = v2 - L;
        }
    }
}

extern "C" void kernel_launch(void* const* d_in, const int* in_sizes, int n_in,
                              void* d_out, int out_size, void* d_ws, size_t ws_size,
                              hipStream_t stream) {
    const float* x   = (const float*)d_in[0];
    // d_in[1] = edge_index (unused: ChebConv K=1 ignores the Laplacian)
    const float* W0  = (const float*)d_in[2];
    const float* bb0 = (const float*)d_in[3];
    const float* W1  = (const float*)d_in[4];
    const float* bb1 = (const float*)d_in[5];
    const float* W2  = (const float*)d_in[6];
    const float* bb2 = (const float*)d_in[7];
    const float* W3  = (const float*)d_in[8];
    const float* bb3 = (const float*)d_in[9];
    short* wt  = (short*)d_ws;         // 110592 B of bf16 transposed weights + bias stash
    float* out = (float*)d_out;

    hipLaunchKernelGGL(prep_weights_k, dim3(216), dim3(256), 0, stream,
                       W0, W1, W2, W3, bb0, bb1, bb2, wt);
    hipLaunchKernelGGL(mlp_fused_k, dim3(NBLK), dim3(832), 0, stream,
                       x, wt, bb3, out);
}